// Round 2
// baseline (873.965 us; speedup 1.0000x reference)
//
#include <hip/hip_runtime.h>
#include <cmath>

#define T_TOK 4096
#define DM 1024
#define DFF 2816

typedef __bf16 bfx8 __attribute__((ext_vector_type(8)));
typedef float f32x4 __attribute__((ext_vector_type(4)));

__device__ __forceinline__ float bf2f(unsigned short u) {
    unsigned int x = ((unsigned int)u) << 16;
    return __uint_as_float(x);
}
__device__ __forceinline__ unsigned short f2bf(float f) {
    unsigned int b = __float_as_uint(f);
    return (unsigned short)((b + 0x7fffu + ((b >> 16) & 1u)) >> 16);
}
// convert 8 contiguous fp32 -> 8 bf16 packed in uint4
__device__ __forceinline__ uint4 pack8(const float* p) {
    float4 a = *(const float4*)p, b = *(const float4*)(p + 4);
    uint4 r;
    r.x = (unsigned)f2bf(a.x) | ((unsigned)f2bf(a.y) << 16);
    r.y = (unsigned)f2bf(a.z) | ((unsigned)f2bf(a.w) << 16);
    r.z = (unsigned)f2bf(b.x) | ((unsigned)f2bf(b.y) << 16);
    r.w = (unsigned)f2bf(b.z) | ((unsigned)f2bf(b.w) << 16);
    return r;
}

// ---------------- dtype probe + zero counters ----------------
// bf16 N(0,1) data: ~all ushorts have exp field in [110,134]. fp32 data viewed
// as ushorts: only ~55% do (mantissa halves are random). flag: 0=bf16, 1=fp32.
__global__ void kProbe(const unsigned short* __restrict__ x, int* flag, int* counts, int* counts2) {
    __shared__ int cnt;
    if (threadIdx.x == 0) cnt = 0;
    __syncthreads();
    int sane = 0;
#pragma unroll
    for (int i = 0; i < 8; i++) {
        unsigned short u = x[threadIdx.x * 8 + i];
        int e = (u >> 7) & 0xFF;
        if (e >= 110 && e <= 134) sane++;
    }
    atomicAdd(&cnt, sane);
    __syncthreads();
    if (threadIdx.x == 0) flag[0] = (cnt >= 1843) ? 0 : 1;   // >=90% sane -> bf16
    if (threadIdx.x < 8) { counts[threadIdx.x] = 0; counts2[threadIdx.x] = 0; }
}

// ---------------- RMSNorm + gating (fp64, exact in both dtype modes) ----------------
__global__ __launch_bounds__(256) void kA(
    const void* __restrict__ xraw, const void* __restrict__ gwraw, const int* __restrict__ flag,
    float* __restrict__ accum, unsigned short* __restrict__ xnorm,
    int* __restrict__ counts, int* __restrict__ t2i, float* __restrict__ t2w)
{
    int f = flag[0];
    int t = blockIdx.x, tid = threadIdx.x;
    int wid = tid >> 6, lane = tid & 63;

    double xv[4]; double ss = 0.0;
    if (f) {
        const float* xr = (const float*)xraw + (size_t)t * DM;
#pragma unroll
        for (int i = 0; i < 4; i++) { xv[i] = (double)xr[tid + 256 * i]; ss += xv[i] * xv[i]; }
    } else {
        const unsigned short* xr = (const unsigned short*)xraw + (size_t)t * DM;
#pragma unroll
        for (int i = 0; i < 4; i++) { xv[i] = (double)bf2f(xr[tid + 256 * i]); ss += xv[i] * xv[i]; }
    }
#pragma unroll
    for (int o = 32; o > 0; o >>= 1) ss += __shfl_down(ss, o);

    __shared__ double sred[4];
    __shared__ double sscale;
    if (lane == 0) sred[wid] = ss;
    __syncthreads();
    if (tid == 0) {
        double tot = sred[0] + sred[1] + sred[2] + sred[3];
        sscale = 1.0 / sqrt(tot / (double)DM + 1e-6);
    }
    __syncthreads();
    double scale = sscale;

#pragma unroll
    for (int i = 0; i < 4; i++) {
        int idx = tid + 256 * i;
        accum[(size_t)t * DM + idx] = (float)xv[i];                 // identity preload
        xnorm[(size_t)t * DM + idx] = f2bf((float)(xv[i] * scale)); // bf16 x_norm for GEMMs
    }

    // gate logits, fp64
    const float* gw32 = (const float*)gwraw;
    const unsigned short* gw16 = (const unsigned short*)gwraw;
    double p[8];
#pragma unroll
    for (int e = 0; e < 8; e++) p[e] = 0.0;
#pragma unroll
    for (int i = 0; i < 4; i++) {
        int idx = tid + 256 * i;
#pragma unroll
        for (int e = 0; e < 8; e++) {
            double w = f ? (double)gw32[e * DM + idx] : (double)bf2f(gw16[e * DM + idx]);
            p[e] += xv[i] * w;
        }
    }
    __shared__ double gred[4][8];
#pragma unroll
    for (int e = 0; e < 8; e++) {
        double v = p[e];
#pragma unroll
        for (int o = 32; o > 0; o >>= 1) v += __shfl_down(v, o);
        if (lane == 0) gred[wid][e] = v;
    }
    __syncthreads();
    if (tid == 0) {
        double l[8], m = -1e300;
        for (int e = 0; e < 8; e++) {
            l[e] = scale * (gred[0][e] + gred[1][e] + gred[2][e] + gred[3][e]);
            if (l[e] > m) m = l[e];
        }
        double pe[8];
        for (int e = 0; e < 8; e++) pe[e] = exp(l[e] - m);
        int a = 0;
        for (int e = 1; e < 8; e++) if (pe[e] > pe[a]) a = e;   // first max on ties (jax top_k)
        int b = (a == 0) ? 1 : 0;
        for (int e = 0; e < 8; e++) { if (e == a) continue; if (pe[e] > pe[b]) b = e; }
        double s2 = pe[a] + pe[b];
        t2i[2 * t] = a; t2i[2 * t + 1] = b;
        t2w[2 * t] = (float)(pe[a] / s2); t2w[2 * t + 1] = (float)(pe[b] / s2);
        atomicAdd(&counts[a], 1); atomicAdd(&counts[b], 1);
    }
}

// ---------------- prefix-sum expert bases ----------------
__global__ void kA2(const int* counts, int* base) {
    if (threadIdx.x == 0) {
        int acc = 0;
        for (int e = 0; e < 8; e++) { base[e] = acc; acc += counts[e]; }
    }
}

// ---------------- build compact row lists ----------------
__global__ __launch_bounds__(256) void kA3(
    const int* __restrict__ t2i, const float* __restrict__ t2w, const int* __restrict__ base,
    int* counts2, int* __restrict__ rows_token, float* __restrict__ rows_w)
{
    int t = blockIdx.x * 256 + threadIdx.x;
    if (t < T_TOK) {
#pragma unroll
        for (int s = 0; s < 2; s++) {
            int e = t2i[2 * t + s];
            int pos = atomicAdd(&counts2[e], 1);
            int row = base[e] + pos;
            rows_token[row] = t; rows_w[row] = t2w[2 * t + s];
        }
        rows_token[2 * T_TOK + t] = t;   // shared expert rows
        rows_w[2 * T_TOK + t] = 1.0f;
    }
}

// ---------------- dual GEMM (w1,w3) + GELU*mul -> h (ff-chunk [c0, c0+CF)) ----------------
__global__ __launch_bounds__(256) void kB(
    const unsigned short* __restrict__ xnorm,
    const void* __restrict__ w1, const void* __restrict__ w3,
    const void* __restrict__ sw1, const void* __restrict__ sw3,
    const int* __restrict__ flag, const int* __restrict__ counts, const int* __restrict__ base,
    const int* __restrict__ rows_token, unsigned short* __restrict__ h, int c0, int CF)
{
    int f = flag[0];
    int e = blockIdx.z;
    int nr, rb; const unsigned short *W1u, *W3u; const float *W1f, *W3f;
    if (e < 8) {
        nr = counts[e]; rb = base[e];
        size_t eb = (size_t)e * DFF * DM;
        W1u = (const unsigned short*)w1 + eb; W3u = (const unsigned short*)w3 + eb;
        W1f = (const float*)w1 + eb;          W3f = (const float*)w3 + eb;
    } else {
        nr = T_TOK; rb = 2 * T_TOK;
        W1u = (const unsigned short*)sw1; W3u = (const unsigned short*)sw3;
        W1f = (const float*)sw1;          W3f = (const float*)sw3;
    }
    int r0 = blockIdx.y * 128;
    if (r0 >= nr) return;
    int n0l = blockIdx.x * 64;           // chunk-local ff offset

    __shared__ __align__(16) unsigned short sA[128 * 72];
    __shared__ __align__(16) unsigned short sB1[64 * 72];
    __shared__ __align__(16) unsigned short sB3[64 * 72];

    int tid = threadIdx.x, wid = tid >> 6, lane = tid & 63;
    int srow = tid >> 3, scol = (tid & 7) * 8;
    int q = lane >> 4, ln = lane & 15;

    const unsigned short* aptr[4];
#pragma unroll
    for (int t = 0; t < 4; t++) {
        int r = r0 + srow + t * 32;
        int tk = rows_token[rb + ((r < nr) ? r : 0)];
        aptr[t] = xnorm + (size_t)tk * DM + scol;
    }
    size_t boff[2];
#pragma unroll
    for (int t = 0; t < 2; t++)
        boff[t] = (size_t)(c0 + n0l + srow + t * 32) * DM + scol;

    f32x4 acc1[2][4], acc3[2][4];
#pragma unroll
    for (int i = 0; i < 2; i++)
#pragma unroll
        for (int j = 0; j < 4; j++) { acc1[i][j] = 0.0f; acc3[i][j] = 0.0f; }

    for (int ko = 0; ko < DM; ko += 64) {
#pragma unroll
        for (int t = 0; t < 4; t++)
            *(uint4*)&sA[(srow + t * 32) * 72 + scol] = *(const uint4*)(aptr[t] + ko);
        if (!f) {
#pragma unroll
            for (int t = 0; t < 2; t++) {
                *(uint4*)&sB1[(srow + t * 32) * 72 + scol] = *(const uint4*)(W1u + boff[t] + ko);
                *(uint4*)&sB3[(srow + t * 32) * 72 + scol] = *(const uint4*)(W3u + boff[t] + ko);
            }
        } else {
#pragma unroll
            for (int t = 0; t < 2; t++) {
                *(uint4*)&sB1[(srow + t * 32) * 72 + scol] = pack8(W1f + boff[t] + ko);
                *(uint4*)&sB3[(srow + t * 32) * 72 + scol] = pack8(W3f + boff[t] + ko);
            }
        }
        __syncthreads();
#pragma unroll
        for (int ks = 0; ks < 2; ks++) {
            bfx8 aF[2], b1F[4], b3F[4];
#pragma unroll
            for (int mt = 0; mt < 2; mt++)
                aF[mt] = *(const bfx8*)&sA[(wid * 32 + mt * 16 + ln) * 72 + ks * 32 + q * 8];
#pragma unroll
            for (int nt = 0; nt < 4; nt++) {
                b1F[nt] = *(const bfx8*)&sB1[(nt * 16 + ln) * 72 + ks * 32 + q * 8];
                b3F[nt] = *(const bfx8*)&sB3[(nt * 16 + ln) * 72 + ks * 32 + q * 8];
            }
#pragma unroll
            for (int mt = 0; mt < 2; mt++)
#pragma unroll
                for (int nt = 0; nt < 4; nt++) {
                    acc1[mt][nt] = __builtin_amdgcn_mfma_f32_16x16x32_bf16(aF[mt], b1F[nt], acc1[mt][nt], 0, 0, 0);
                    acc3[mt][nt] = __builtin_amdgcn_mfma_f32_16x16x32_bf16(aF[mt], b3F[nt], acc3[mt][nt], 0, 0, 0);
                }
        }
        __syncthreads();
    }

#pragma unroll
    for (int mt = 0; mt < 2; mt++)
#pragma unroll
        for (int nt = 0; nt < 4; nt++)
#pragma unroll
            for (int r = 0; r < 4; r++) {
                int gr = r0 + wid * 32 + mt * 16 + q * 4 + r;
                if (gr < nr) {
                    float a = acc1[mt][nt][r], b3v = acc3[mt][nt][r];
                    float g = 0.5f * a * (1.0f + erff(a * 0.70710678118654752f));
                    h[(size_t)(rb + gr) * CF + n0l + nt * 16 + ln] = f2bf(g * b3v);
                }
            }
}

// ---------------- GEMM h @ w2^T (k-chunk [c0,c0+CF)), scale, atomic accumulate ----------------
__global__ __launch_bounds__(256) void kC(
    const unsigned short* __restrict__ h,
    const void* __restrict__ w2, const void* __restrict__ sw2,
    const int* __restrict__ flag, const int* __restrict__ counts, const int* __restrict__ base,
    const int* __restrict__ rows_token, const float* __restrict__ rows_w,
    float* __restrict__ accum, int c0, int CF)
{
    int f = flag[0];
    int e = blockIdx.z;
    int nr, rb; const unsigned short* W2u; const float* W2f;
    if (e < 8) {
        nr = counts[e]; rb = base[e];
        size_t eb = (size_t)e * DM * DFF;
        W2u = (const unsigned short*)w2 + eb; W2f = (const float*)w2 + eb;
    } else {
        nr = T_TOK; rb = 2 * T_TOK;
        W2u = (const unsigned short*)sw2; W2f = (const float*)sw2;
    }
    int r0 = blockIdx.y * 128;
    if (r0 >= nr) return;
    int n0 = blockIdx.x * 64;

    __shared__ __align__(16) unsigned short sA[128 * 72];
    __shared__ __align__(16) unsigned short sB[64 * 72];

    int tid = threadIdx.x, wid = tid >> 6, lane = tid & 63;
    int srow = tid >> 3, scol = (tid & 7) * 8;
    int q = lane >> 4, ln = lane & 15;

    size_t aoff[4];
#pragma unroll
    for (int t = 0; t < 4; t++) {
        int r = r0 + srow + t * 32;
        int rr = (r < nr) ? r : 0;
        aoff[t] = (size_t)(rb + rr) * CF + scol;
    }
    size_t boff[2];
#pragma unroll
    for (int t = 0; t < 2; t++)
        boff[t] = (size_t)(n0 + srow + t * 32) * DFF + c0 + scol;

    f32x4 acc[2][4];
#pragma unroll
    for (int i = 0; i < 2; i++)
#pragma unroll
        for (int j = 0; j < 4; j++) acc[i][j] = 0.0f;

    for (int ko = 0; ko < CF; ko += 64) {
#pragma unroll
        for (int t = 0; t < 4; t++)
            *(uint4*)&sA[(srow + t * 32) * 72 + scol] = *(const uint4*)(h + aoff[t] + ko);
        if (!f) {
#pragma unroll
            for (int t = 0; t < 2; t++)
                *(uint4*)&sB[(srow + t * 32) * 72 + scol] = *(const uint4*)(W2u + boff[t] + ko);
        } else {
#pragma unroll
            for (int t = 0; t < 2; t++)
                *(uint4*)&sB[(srow + t * 32) * 72 + scol] = pack8(W2f + boff[t] + ko);
        }
        __syncthreads();
#pragma unroll
        for (int ks = 0; ks < 2; ks++) {
            bfx8 aF[2], bF[4];
#pragma unroll
            for (int mt = 0; mt < 2; mt++)
                aF[mt] = *(const bfx8*)&sA[(wid * 32 + mt * 16 + ln) * 72 + ks * 32 + q * 8];
#pragma unroll
            for (int nt = 0; nt < 4; nt++)
                bF[nt] = *(const bfx8*)&sB[(nt * 16 + ln) * 72 + ks * 32 + q * 8];
#pragma unroll
            for (int mt = 0; mt < 2; mt++)
#pragma unroll
                for (int nt = 0; nt < 4; nt++)
                    acc[mt][nt] = __builtin_amdgcn_mfma_f32_16x16x32_bf16(aF[mt], bF[nt], acc[mt][nt], 0, 0, 0);
        }
        __syncthreads();
    }

#pragma unroll
    for (int mt = 0; mt < 2; mt++)
#pragma unroll
        for (int r = 0; r < 4; r++) {
            int gr = r0 + wid * 32 + mt * 16 + q * 4 + r;
            if (gr < nr) {
                float w = rows_w[rb + gr];
                int tk = rows_token[rb + gr];
#pragma unroll
                for (int nt = 0; nt < 4; nt++)
                    atomicAdd(&accum[(size_t)tk * DM + n0 + nt * 16 + ln], acc[mt][nt][r] * w);
            }
        }
}

// ---------------- fp32 accum -> out (dtype per flag) ----------------
__global__ __launch_bounds__(256) void kD(const float* __restrict__ accum, void* __restrict__ outraw,
                                          const int* __restrict__ flag) {
    int f = flag[0];
    int i = (blockIdx.x * 256 + threadIdx.x) * 4;
    float4 v = *(const float4*)&accum[i];
    if (f) {
        *(float4*)((float*)outraw + i) = v;
    } else {
        ushort4 u;
        u.x = f2bf(v.x); u.y = f2bf(v.y); u.z = f2bf(v.z); u.w = f2bf(v.w);
        *(ushort4*)((unsigned short*)outraw + i) = u;
    }
}

extern "C" void kernel_launch(void* const* d_in, const int* in_sizes, int n_in,
                              void* d_out, int out_size, void* d_ws, size_t ws_size,
                              hipStream_t stream)
{
    const void* x   = d_in[0];
    const void* gw  = d_in[1];
    const void* w1  = d_in[2];
    const void* w2  = d_in[3];
    const void* w3  = d_in[4];
    const void* sw1 = d_in[5];
    const void* sw2 = d_in[6];
    const void* sw3 = d_in[7];

    char* ws = (char*)d_ws;
    size_t off = 0;
    auto alloc = [&](size_t bytes) { void* p = ws + off; off += (bytes + 255) & ~(size_t)255; return p; };
    int* flag             = (int*)alloc(256);
    unsigned short* xnorm = (unsigned short*)alloc((size_t)T_TOK * DM * 2);
    float* accum          = (float*)alloc((size_t)T_TOK * DM * 4);
    int* counts           = (int*)alloc(256);
    int* counts2          = (int*)alloc(256);
    int* base             = (int*)alloc(256);
    int* rows_token       = (int*)alloc((size_t)3 * T_TOK * 4);
    float* rows_w         = (float*)alloc((size_t)3 * T_TOK * 4);
    int* t2i              = (int*)alloc((size_t)T_TOK * 2 * 4);
    float* t2w            = (float*)alloc((size_t)T_TOK * 2 * 4);

    // choose largest ff-chunk that fits ws: h = 3*T_TOK rows x CF bf16
    static const int ncs[6] = {1, 2, 4, 11, 22, 44};
    int NC = 44;
    for (int i = 0; i < 6; i++) {
        size_t hb = (size_t)3 * T_TOK * (DFF / ncs[i]) * 2;
        if (off + hb <= ws_size) { NC = ncs[i]; break; }
    }
    int CF = DFF / NC;
    unsigned short* h = (unsigned short*)alloc((size_t)3 * T_TOK * CF * 2);

    kProbe<<<1, 256, 0, stream>>>((const unsigned short*)x, flag, counts, counts2);
    kA<<<T_TOK, 256, 0, stream>>>(x, gw, flag, accum, xnorm, counts, t2i, t2w);
    kA2<<<1, 64, 0, stream>>>(counts, base);
    kA3<<<(T_TOK + 255) / 256, 256, 0, stream>>>(t2i, t2w, base, counts2, rows_token, rows_w);
    for (int c = 0; c < NC; c++) {
        kB<<<dim3(CF / 64, 32, 9), 256, 0, stream>>>(xnorm, w1, w3, sw1, sw3, flag, counts, base,
                                                     rows_token, h, c * CF, CF);
        kC<<<dim3(DM / 64, 32, 9), 256, 0, stream>>>(h, w2, sw2, flag, counts, base,
                                                     rows_token, rows_w, accum, c * CF, CF);
    }
    kD<<<(T_TOK * DM) / 1024, 256, 0, stream>>>(accum, d_out, flag);
}